// Round 11
// baseline (37.151 us; speedup 1.0000x reference)
//
#include <hip/hip_runtime.h>
#include <math.h>
#include <climits>

#define BLOCK 256
#define NCHUNK 5
#define REGCAP (NCHUNK * 1024)          // 5120 aligned elements per block
#define LARGE_NEG (-1.0e9f)
#define SCORE_EPS 1e-6f
#define RANDP 0.1f
#define PROB_EPS 1e-12f
#define F32EPS 1.1920928955078125e-7f   // torch.finfo(float32).eps

// scalar windowed lower_bound: first idx with batch[idx] >= target.
// Window ghat +/- 16384 (>11 sigma for multinomial edge counts), verified,
// full-range fallback so correctness never depends on the distribution.
__device__ __forceinline__ int scalar_lb(const int* __restrict__ batch,
                                         int E, int G, int target) {
  const long long ghat =
      (long long)target * (long long)E / (long long)(G > 0 ? G : 1);
  long long wlo = ghat - 16384, whi = ghat + 16384;
  int lo = wlo > 0 ? (int)wlo : 0;
  int hi = whi < (long long)E ? (int)whi : E;
  while (lo < hi) {
    const int mid = (lo + hi) >> 1;
    if (batch[mid] < target) lo = mid + 1; else hi = mid;
  }
  bool ok = (lo == 0 || batch[lo - 1] < target) &&
            (lo == E || batch[lo] >= target);
  if (!ok) {                            // window missed: full-range redo
    lo = 0; hi = E;
    while (lo < hi) {
      const int mid = (lo + hi) >> 1;
      if (batch[mid] < target) lo = mid + 1; else hi = mid;
    }
  }
  return lo;
}

// ---------- single kernel: one workgroup per graph -------------------------
// Prologue (concurrent, one barrier): thread 0 -> start = lb(g); thread 64 ->
//   end = lb(g+1); wave 2 -> valid_edges format detect on shared 1KB sample.
// Body: u-transform. u = w*exp(r)  =>  exp(combined logit + ld1) == u exactly.
//   - stage-2 denominator: plain sum of u (no online softmax, no exp chain)
//   - tmax = log(umax) (one scalar log); argmax by u (monotone equivalence)
//   - output clean = log(u) - off3 (log deferred to store pass)
//   Per-element transcendentals: 1 exp (load) + 1 log (store); all reduce
//   merges are fmax/add. Invalid marker: u = -1 (valid u >= 1e-38 > 0).
__global__ __launch_bounds__(BLOCK) void
gfn_main(const float* __restrict__ scores,
         const float* __restrict__ resid,
         const float* __restrict__ stop_resid,
         const void* __restrict__ validp,
         const int* __restrict__ batch,
         float* __restrict__ out, int E, int G) {
  __shared__ float redf[24];
  __shared__ int redi[4];
  __shared__ int sb[2];
  __shared__ int sflag;

  const int g = blockIdx.x;
  const unsigned char* vb = (const unsigned char*)validp;
  const int* vi = (const int*)validp;
  const int wid = (int)(threadIdx.x >> 6);
  const int lane = (int)(threadIdx.x & 63);

  // ---- fused prologue ----
  if (threadIdx.x == 0) {
    sb[0] = scalar_lb(batch, E, G, g);
  } else if (threadIdx.x == 64) {
    sb[1] = scalar_lb(batch, E, G, g + 1);
  } else if (wid == 2) {
    const unsigned int* vwords = (const unsigned int*)validp;
    const int sampleBytes = (E < 1024) ? (E & ~3) : 1024;
    const int nwords = sampleBytes >> 2;
    int cnt = 0;
    for (int w = lane; w < nwords; w += 64) {
      const unsigned int x = vwords[w];
      cnt += ((x & 0x000000FFu) != 0) + ((x & 0x0000FF00u) != 0) +
             ((x & 0x00FF0000u) != 0) + ((x & 0xFF000000u) != 0);
    }
#pragma unroll
    for (int o = 32; o >= 1; o >>= 1) cnt += __shfl_xor(cnt, o);
    if (lane == 0) sflag = (2 * cnt > sampleBytes) ? 1 : 0;
  }
  __syncthreads();
  const int start = sb[0];
  const int end = sb[1];
  const bool byteFmt = (sflag != 0);
  const int abase = start & ~3;          // 16B-aligned segment base

  if ((E & 3) == 0 && (end - abase) <= REGCAP) {
    // =================== fast path: u in registers =========================
    const int t4 = (int)threadIdx.x * 4;
    float c[NCHUNK][4];                  // u (or -1 invalid), static indexing
    float smax = 0.f, ssum = 0.f;
    float umax = 0.f, usum = 0.f;        // plain (max, sum) over u
    int vcnt = 0;
    float bv = -INFINITY;                // argmax over u (monotone equiv)
    int bi = INT_MAX;

#pragma unroll
    for (int j = 0; j < NCHUNK; ++j) {
      const int e0 = abase + j * 1024 + t4;
      if (e0 < end) {   // e0%4==0 & E%4==0 -> e0+3 <= E-1 (safe f4 load)
        const float4 s4 = *(const float4*)(scores + e0);
        const float4 r4 = *(const float4*)(resid + e0);
        unsigned int m;
        if (byteFmt) {
          const unsigned int uu = *(const unsigned int*)(vb + e0);
          m = ((uu & 0x000000FFu) ? 1u : 0u) | ((uu & 0x0000FF00u) ? 2u : 0u) |
              ((uu & 0x00FF0000u) ? 4u : 0u) | ((uu & 0xFF000000u) ? 8u : 0u);
        } else {
          const int4 uu = *(const int4*)(vi + e0);
          m = (uu.x ? 1u : 0u) | (uu.y ? 2u : 0u) | (uu.z ? 4u : 0u) | (uu.w ? 8u : 0u);
        }
        const float ss[4] = {s4.x, s4.y, s4.z, s4.w};
        const float rr[4] = {r4.x, r4.y, r4.z, r4.w};
#pragma unroll
        for (int k = 0; k < 4; ++k) {
          const int e = e0 + k;
          const bool ok = ((m >> k) & 1u) && (e >= start) && (e < end);
          float u = -1.f;
          if (ok) {
            const float w = fmaxf(ss[k], SCORE_EPS);
            smax = fmaxf(smax, w);
            ssum += w;
            ++vcnt;
            u = fmaxf(w * __expf(rr[k]), 1e-38f);  // flush-guard: log stays finite
            umax = fmaxf(umax, u);
            usum += u;
            if (u > bv || (u == bv && e < bi)) { bv = u; bi = e; }
          }
          c[j][k] = u;
        }
      } else {
#pragma unroll
        for (int k = 0; k < 4; ++k) c[j][k] = -1.f;
      }
    }

    // ---- single fused reduce: all merges are fmax/add ---------------------
#pragma unroll
    for (int o = 32; o >= 1; o >>= 1) {
      smax = fmaxf(smax, __shfl_xor(smax, o));
      ssum += __shfl_xor(ssum, o);
      vcnt += __shfl_xor(vcnt, o);
      umax = fmaxf(umax, __shfl_xor(umax, o));
      usum += __shfl_xor(usum, o);
      const float v2 = __shfl_xor(bv, o);
      const int i2 = __shfl_xor(bi, o);
      if (v2 > bv || (v2 == bv && i2 < bi)) { bv = v2; bi = i2; }
    }
    if (lane == 0) {
      redf[wid] = smax; redf[4 + wid] = ssum; redf[8 + wid] = (float)vcnt;
      redf[12 + wid] = umax; redf[16 + wid] = usum; redf[20 + wid] = bv;
      redi[wid] = bi;
    }
    __syncthreads();
    smax = fmaxf(fmaxf(redf[0], redf[1]), fmaxf(redf[2], redf[3]));
    ssum = (redf[4] + redf[5]) + (redf[6] + redf[7]);
    const float vc = (redf[8] + redf[9]) + (redf[10] + redf[11]);
    umax = fmaxf(fmaxf(redf[12], redf[13]), fmaxf(redf[14], redf[15]));
    usum = (redf[16] + redf[17]) + (redf[18] + redf[19]);
    bv = redf[20]; bi = redi[0];
#pragma unroll
    for (int w = 1; w < 4; ++w) {
      const float v2 = redf[20 + w]; const int i2 = redi[w];
      if (v2 > bv || (v2 == bv && i2 < bi)) { bv = v2; bi = i2; }
    }

    // ---- per-graph scalars (every thread; all scalar math) ----------------
    // ld1 = log M + log(ssum/M + 1/M + EPS) = log(ssum + 1 + M*EPS)
    // m2  = max combined logit = log(umax) - ld1   (-inf if no valid: ok)
    // exp_edges(mj2 scale) = usum * exp(-(ld1+mj2))  <= vcnt (bounded)
    const float M = fmaxf(smax, 1.f);
    const float ld1 = __logf(ssum + 1.f + M * F32EPS);
    const float m2 = __logf(umax) - ld1;
    const float ss2 = stop_resid[g] - ld1;   // combined stop logit
    const float mj2 = fmaxf(m2, ss2);
    const float exp_edges = usum * __expf(-(ld1 + mj2));
    const float ld2 = mj2 + __logf(exp_edges + __expf(ss2 - mj2) + F32EPS);
    const float clean_stop = ss2 - ld2;
    const float invt = 1.f / fmaxf(vc + 1.f, 1.f);
    const float off3 = ld1 + ld2;            // clean = log(u) - off3

    // ---- store pass: clean_log_edge = log(u) - off3 -----------------------
#pragma unroll
    for (int j = 0; j < NCHUNK; ++j) {
      const int e0 = abase + j * 1024 + t4;
      if (e0 < end) {
        float ov[4];
#pragma unroll
        for (int k = 0; k < 4; ++k) {
          const float u = c[j][k];
          ov[k] = (u >= 0.f) ? (__logf(u) - off3) : LARGE_NEG;
        }
        if (e0 >= start && e0 + 4 <= end) {
          *(float4*)(out + e0) = make_float4(ov[0], ov[1], ov[2], ov[3]);
        } else {
#pragma unroll
          for (int k = 0; k < 4; ++k) {
            const int e = e0 + k;
            if (e >= start && e < end) out[e] = ov[k];
          }
        }
      }
    }
    if (threadIdx.x == 0) {
      const bool anyvalid = (bi != INT_MAX);
      float bvls = LARGE_NEG;              // best log_sample_edge (ref formula)
      float wclean = 0.f;
      if (anyvalid) {
        wclean = __logf(bv) - off3;        // winner's clean_log_edge
        const float p = (1.f - RANDP) * __expf(wclean) + RANDP * invt;
        bvls = __logf(fmaxf(p, PROB_EPS));
      }
      const float ssp = (1.f - RANDP) * __expf(clean_stop) + RANDP * invt;
      const float lss = __logf(fmaxf(ssp, PROB_EPS));
      const bool take_stop = (lss >= bvls);
      out[E + g]         = clean_stop;                         // output 1
      out[E + G + g]     = take_stop ? (float)end : (float)bi; // output 2
      out[E + 2 * G + g] = take_stop ? clean_stop : wclean;    // output 3
    }
    return;
  }

  // =================== fallback: 5-pass global reread (n > REGCAP) =========
  const int n = end - start;
  auto load_l = [&](int e) -> float {
    float s = scores[e];
    int v = byteFmt ? (int)vb[e] : vi[e];
    return v ? __logf(fmaxf(s, SCORE_EPS)) : LARGE_NEG;
  };

  float m1 = LARGE_NEG, vc = 0.f;
  for (int i = threadIdx.x; i < n; i += BLOCK) {
    float l = load_l(start + i);
    m1 = fmaxf(m1, l);
    if (l != LARGE_NEG) vc += 1.f;
  }
#pragma unroll
  for (int o = 32; o >= 1; o >>= 1) {
    m1 = fmaxf(m1, __shfl_xor(m1, o));
    vc += __shfl_xor(vc, o);
  }
  if (lane == 0) { redf[wid] = m1; redf[4 + wid] = vc; }
  __syncthreads();
  m1 = fmaxf(fmaxf(redf[0], redf[1]), fmaxf(redf[2], redf[3]));
  vc = (redf[4] + redf[5]) + (redf[6] + redf[7]);
  __syncthreads();

  const float mj1 = fmaxf(m1, 0.f);
  float s1 = 0.f;
  for (int i = threadIdx.x; i < n; i += BLOCK)
    s1 += __expf(load_l(start + i) - mj1);
#pragma unroll
  for (int o = 32; o >= 1; o >>= 1) s1 += __shfl_xor(s1, o);
  if (lane == 0) redf[wid] = s1;
  __syncthreads();
  s1 = (redf[0] + redf[1]) + (redf[2] + redf[3]);
  __syncthreads();
  const float ld1 = mj1 + __logf(s1 + __expf(-mj1) + F32EPS);

  float m2 = LARGE_NEG;
  for (int i = threadIdx.x; i < n; i += BLOCK) {
    float l = load_l(start + i);
    float cc = (l != LARGE_NEG) ? (l - ld1 + resid[start + i]) : LARGE_NEG;
    m2 = fmaxf(m2, cc);
  }
#pragma unroll
  for (int o = 32; o >= 1; o >>= 1) m2 = fmaxf(m2, __shfl_xor(m2, o));
  if (lane == 0) redf[wid] = m2;
  __syncthreads();
  m2 = fmaxf(fmaxf(redf[0], redf[1]), fmaxf(redf[2], redf[3]));
  __syncthreads();

  const float ss2 = stop_resid[g] - ld1;
  const float mj2 = fmaxf(m2, ss2);
  float s2 = 0.f;
  for (int i = threadIdx.x; i < n; i += BLOCK) {
    float l = load_l(start + i);
    float cc = (l != LARGE_NEG) ? (l - ld1 + resid[start + i]) : LARGE_NEG;
    s2 += __expf(cc - mj2);
  }
#pragma unroll
  for (int o = 32; o >= 1; o >>= 1) s2 += __shfl_xor(s2, o);
  if (lane == 0) redf[wid] = s2;
  __syncthreads();
  s2 = (redf[0] + redf[1]) + (redf[2] + redf[3]);
  __syncthreads();
  const float ld2 = mj2 + __logf(s2 + __expf(ss2 - mj2) + F32EPS);
  const float clean_stop = ss2 - ld2;
  const float invt = 1.f / fmaxf(vc + 1.f, 1.f);

  float bv = -INFINITY; int bi = INT_MAX; float bc = 0.f;
  for (int i = threadIdx.x; i < n; i += BLOCK) {
    const int e = start + i;
    float l = load_l(e);
    float cc = (l != LARGE_NEG) ? (l - ld1 + resid[e]) : LARGE_NEG;
    const bool v = (cc != LARGE_NEG);
    const float clean = cc - ld2;
    out[e] = v ? clean : LARGE_NEG;
    float ls;
    if (v) {
      const float p = (1.f - RANDP) * __expf(clean) + RANDP * invt;
      ls = __logf(fmaxf(p, PROB_EPS));
    } else ls = LARGE_NEG;
    if (ls > bv || (ls == bv && e < bi)) { bv = ls; bi = e; bc = clean; }
  }
#pragma unroll
  for (int o = 32; o >= 1; o >>= 1) {
    const float v2 = __shfl_xor(bv, o);
    const int i2 = __shfl_xor(bi, o);
    const float c2 = __shfl_xor(bc, o);
    if (v2 > bv || (v2 == bv && i2 < bi)) { bv = v2; bi = i2; bc = c2; }
  }
  if (lane == 0) { redf[wid] = bv; redf[4 + wid] = bc; redi[wid] = bi; }
  __syncthreads();
  if (threadIdx.x == 0) {
    bv = redf[0]; bi = redi[0]; bc = redf[4];
    for (int w = 1; w < 4; ++w) {
      if (redf[w] > bv || (redf[w] == bv && redi[w] < bi)) {
        bv = redf[w]; bi = redi[w]; bc = redf[4 + w];
      }
    }
    const float ssp = (1.f - RANDP) * __expf(clean_stop) + RANDP * invt;
    const float lss = __logf(fmaxf(ssp, PROB_EPS));
    const bool take_stop = (lss >= bv);
    out[E + g]         = clean_stop;
    out[E + G + g]     = take_stop ? (float)end : (float)bi;
    out[E + 2 * G + g] = take_stop ? clean_stop : bc;
  }
}

extern "C" void kernel_launch(void* const* d_in, const int* in_sizes, int n_in,
                              void* d_out, int out_size, void* d_ws, size_t ws_size,
                              hipStream_t stream) {
  const float* scores     = (const float*)d_in[0];
  const float* resid      = (const float*)d_in[1];
  const float* stop_resid = (const float*)d_in[2];
  const void*  validp     = d_in[3];
  const int*   batch      = (const int*)d_in[4];
  const int E = in_sizes[0];
  const int G = in_sizes[2];

  gfn_main<<<G, BLOCK, 0, stream>>>(scores, resid, stop_resid, validp, batch,
                                    (float*)d_out, E, G);
}